// Round 22
// baseline (219.935 us; speedup 1.0000x reference)
//
#include <hip/hip_runtime.h>
#include <hip/hip_bf16.h>
#include <stdint.h>

typedef __attribute__((ext_vector_type(8))) short bf16x8;
typedef __attribute__((ext_vector_type(4))) float f32x4v;
typedef __attribute__((ext_vector_type(16))) float f32x16;
typedef __attribute__((ext_vector_type(4))) unsigned int u32x4;

#define CH_STRIDE 65536  // T*W*H

__device__ __forceinline__ uint16_t f2bf(float f) {
  uint32_t u = __builtin_bit_cast(uint32_t, f);
  u = (u + 0x7FFFu + ((u >> 16) & 1u)) >> 16;
  return (uint16_t)u;
}
__device__ __forceinline__ float bf2f(uint32_t b) {
  return __builtin_bit_cast(float, b << 16);
}
__device__ __forceinline__ uint16_t cvt_bf(float f) {
  return __builtin_bit_cast(uint16_t, __float2bfloat16(f));
}
__device__ __forceinline__ bf16x8 andm(bf16x8 v, uint32_t m) {
  u32x4 u = __builtin_bit_cast(u32x4, v);
  u[0] &= m; u[1] &= m; u[2] &= m; u[3] &= m;
  return __builtin_bit_cast(bf16x8, u);
}

#define MFMA32(a, b, c) __builtin_amdgcn_mfma_f32_32x32x16_bf16(a, b, c, 0, 0, 0)
#define WAIT0 asm volatile("s_waitcnt vmcnt(0) lgkmcnt(0)" ::: "memory")
#define BAR __builtin_amdgcn_s_barrier()
#define SCHED0 __builtin_amdgcn_sched_barrier(0)

#define LDSX6  (6 * 8 * 66 * 16)   // 50688 (q x tile, WITH halo cols)
#define LDSK   (6 * 8 * 64 * 16)   // 49152 (kv x tile, interior only)

// Direct global->LDS DMA, 16B/lane (q weights — linear pattern).
__device__ __forceinline__ void gld16(const void* g, void* l) {
  __builtin_amdgcn_global_load_lds(
      (const __attribute__((address_space(1))) uint32_t*)g,
      (__attribute__((address_space(3))) uint32_t*)l, 16, 0, 0);
}

// q x tile: [row][oct][col66] (halo cols 0,65 zero).
__device__ __forceinline__ bf16x8 ldx(const uint8_t* ldsx, int row, int oct, int ci) {
  return *(const bf16x8*)(ldsx + (uint32_t)((row * 8 + oct) * 66 + ci) * 16u);
}
// kv x tile: [row][oct][col64] interior only; caller clamps/masks.
__device__ __forceinline__ bf16x8 ldx64(const uint8_t* ldsx, int row, int oct, int ci) {
  return *(const bf16x8*)(ldsx + (uint32_t)((row * 8 + oct) * 64 + ci) * 16u);
}
__device__ __forceinline__ bf16x8 ldw_q(const uint8_t* ldsw, int oct, int row) {
  return *(const bf16x8*)(ldsw + (uint32_t)(oct * 64 + row) * 16u);
}
// kv weights read DIRECT from global (tap-contiguous table, L2-resident).
__device__ __forceinline__ bf16x8 ldw_g(const uint16_t* wkv, int tap, int oct, int rowloc) {
  return *(const bf16x8*)(wkv + ((size_t)(tap * 8 + oct) * 128 + rowloc) * 8);
}

// scatter stage (q variant, 66-col with halo)
__device__ __forceinline__ void stage_unit66(uint8_t* ldsx, const float* xs, int w0, int u) {
  int row = u >> 7, oct = (u >> 4) & 7, g = u & 15;
  int w = w0 - 1 + row;
  uint32_t base = (uint32_t)((row * 8 + oct) * 66 + 4 * g + 1) * 16u;
  if ((unsigned)w < 64u) {
    const float* p = xs + (size_t)(oct * 8) * CH_STRIDE + w * 64 + 4 * g;
    f32x4v v[8];
    #pragma unroll
    for (int j = 0; j < 8; ++j) v[j] = *(const f32x4v*)(p + (size_t)j * CH_STRIDE);
    #pragma unroll
    for (int c = 0; c < 4; ++c) {
      bf16x8 frag;
      #pragma unroll
      for (int q = 0; q < 4; ++q) {
        frag[2 * q]     = (short)cvt_bf(v[2 * q][c]);
        frag[2 * q + 1] = (short)cvt_bf(v[2 * q + 1][c]);
      }
      *(bf16x8*)(ldsx + base + (uint32_t)c * 16u) = frag;
    }
  } else {
    bf16x8 z = {};
    #pragma unroll
    for (int c = 0; c < 4; ++c) *(bf16x8*)(ldsx + base + (uint32_t)c * 16u) = z;
  }
}
// scatter stage (kv variant, 64-col interior)
__device__ __forceinline__ void stage_unit64(uint8_t* ldsx, const float* xs, int w0, int u) {
  int row = u >> 7, oct = (u >> 4) & 7, g = u & 15;
  int w = w0 - 1 + row;
  uint32_t base = (uint32_t)((row * 8 + oct) * 64 + 4 * g) * 16u;
  if ((unsigned)w < 64u) {
    const float* p = xs + (size_t)(oct * 8) * CH_STRIDE + w * 64 + 4 * g;
    f32x4v v[8];
    #pragma unroll
    for (int j = 0; j < 8; ++j) v[j] = *(const f32x4v*)(p + (size_t)j * CH_STRIDE);
    #pragma unroll
    for (int c = 0; c < 4; ++c) {
      bf16x8 frag;
      #pragma unroll
      for (int q = 0; q < 4; ++q) {
        frag[2 * q]     = (short)cvt_bf(v[2 * q][c]);
        frag[2 * q + 1] = (short)cvt_bf(v[2 * q + 1][c]);
      }
      *(bf16x8*)(ldsx + base + (uint32_t)c * 16u) = frag;
    }
  } else {
    bf16x8 z = {};
    #pragma unroll
    for (int c = 0; c < 4; ++c) *(bf16x8*)(ldsx + base + (uint32_t)c * 16u) = z;
  }
}
__device__ __forceinline__ void stage_halo66(uint8_t* ldsx, int tid, int nrow) {
  if (tid < nrow * 16) {
    int row = tid >> 4, rem = tid & 15;
    int oct = rem >> 1, side = rem & 1;
    bf16x8 z = {};
    *(bf16x8*)(ldsx + (uint32_t)((row * 8 + oct) * 66 + side * 65) * 16u) = z;
  }
}

// ---------------------------------------------------------------------------
// prep: fp32 [o][i][tap] -> bf16 tap-contiguous tables (q then kv).
// ---------------------------------------------------------------------------
__global__ void prep_weights(const float* __restrict__ wq, const float* __restrict__ wk,
                             const float* __restrict__ wv, uint16_t* __restrict__ wout) {
  int i = blockIdx.x * 256 + threadIdx.x;
  if (i >= 110592) return;
  if (i < 36864) {
    int tap = i >> 12, oct = (i >> 9) & 7, row = (i >> 3) & 63, j = i & 7;
    wout[i] = f2bf(wq[(row * 64 + oct * 8 + j) * 9 + tap]);
  } else {
    int m = i - 36864;
    int tap = m >> 13, oct = (m >> 10) & 7, rl = (m >> 3) & 127, j = m & 7;
    const float* src = (rl < 64) ? wk : wv;
    wout[i] = f2bf(src[((rl & 63) * 64 + oct * 8 + j) * 9 + tap]);
  }
}

// ---------------------------------------------------------------------------
// KV kernel: 256 thr / 4 waves; wave = 1 output row; M=4 weight tiles per
// wave read DIRECT from global (L2/L1-hot) — no weight LDS, no DMA, ZERO
// barriers in the main loop (waves free-run). x in LDS (49KB interior).
// ---------------------------------------------------------------------------
__global__ __launch_bounds__(256, 3) void kv_s_kernel(
    const float* __restrict__ x, const uint16_t* __restrict__ wkv,
    const float* __restrict__ bk, const float* __restrict__ bv,
    float* __restrict__ s_out) {
  extern __shared__ uint8_t lds[];
  uint8_t* ldsx = lds;
  const int tid = threadIdx.x;
  const int l = tid & 63;
  const int ng = tid >> 6;  // wave = output row 0..3
  int bid = (int)(blockIdx.x & 7) * 256 + (int)(blockIdx.x >> 3);  // XCD swizzle
  const int rg = bid & 15, slice = bid >> 4;
  const int b = slice >> 4, t = slice & 15;
  const int w0 = rg * 4;
  const float* xs = x + ((size_t)b * 1024 + t) * 4096;
  const int lm = l & 31, lh = l >> 5;
  const uint32_t mz0 = (lm == 0) ? 0u : ~0u;   // b0 halo mask at dx=0
  const uint32_t mz1 = (lm == 31) ? 0u : ~0u;  // b1 halo mask at dx=2

  #pragma unroll
  for (int k = 0; k < 3; ++k) stage_unit64(ldsx, xs, w0, tid + k * 256);
  __syncthreads();

  f32x16 accK[2][2], accV[2][2];  // [mt channel-half][nt col-half]
  #pragma unroll
  for (int mt = 0; mt < 2; ++mt)
    #pragma unroll
    for (int nt = 0; nt < 2; ++nt)
      #pragma unroll
      for (int q = 0; q < 16; ++q) { accK[mt][nt][q] = 0.f; accV[mt][nt][q] = 0.f; }

  #pragma unroll
  for (int tap = 0; tap < 9; ++tap) {
    const int dy = tap / 3, dx = tap % 3;
    #pragma unroll
    for (int s = 0; s < 4; ++s) {
      int oct = s * 2 + lh;
      bf16x8 aK0 = ldw_g(wkv, tap, oct, lm);
      bf16x8 aK1 = ldw_g(wkv, tap, oct, 32 + lm);
      bf16x8 aV0 = ldw_g(wkv, tap, oct, 64 + lm);
      bf16x8 aV1 = ldw_g(wkv, tap, oct, 96 + lm);
      bf16x8 b0  = ldx64(ldsx, ng + dy, oct, (lm + dx - 1) & 63);
      bf16x8 b1  = ldx64(ldsx, ng + dy, oct, (32 + lm + dx - 1) & 63);
      if (dx == 0) b0 = andm(b0, mz0);
      if (dx == 2) b1 = andm(b1, mz1);
      accK[0][0] = MFMA32(aK0, b0, accK[0][0]);
      accK[0][1] = MFMA32(aK0, b1, accK[0][1]);
      accK[1][0] = MFMA32(aK1, b0, accK[1][0]);
      accK[1][1] = MFMA32(aK1, b1, accK[1][1]);
      accV[0][0] = MFMA32(aV0, b0, accV[0][0]);
      accV[0][1] = MFMA32(aV0, b1, accV[0][1]);
      accV[1][0] = MFMA32(aV1, b0, accV[1][0]);
      accV[1][1] = MFMA32(aV1, b1, accV[1][1]);
    }
  }

  // epilogue: LDS partial-dump (stride 133), 64-thread reduce, 1 atomic/ch
  __syncthreads();
  float* red = (float*)lds;        // [c 64][133] = 34 KB (fits ldsx region)
  #pragma unroll
  for (int q = 0; q < 16; ++q) {
    int cl = (q & 3) + 8 * (q >> 2) + 4 * lh;
    #pragma unroll
    for (int mt = 0; mt < 2; ++mt) {
      int c = mt * 32 + cl;
      float bkc = bk[c], bvc = bv[c];
      float p = (accK[mt][0][q] + bkc) * (accV[mt][0][q] + bvc)
              + (accK[mt][1][q] + bkc) * (accV[mt][1][q] + bvc);
      red[c * 133 + ng * 32 + lm] = p;
    }
  }
  __syncthreads();
  if (tid < 64) {
    const float* rp = red + tid * 133;
    f32x4v a4 = {0.f, 0.f, 0.f, 0.f};
    #pragma unroll
    for (int j = 0; j < 32; ++j) a4 += *(const f32x4v*)(rp + j * 4);
    atomicAdd(s_out + (b * 16 + t) * 64 + tid, a4[0] + a4[1] + a4[2] + a4[3]);
  }
}

// ---------------------------------------------------------------------------
// Q kernel: unchanged from R21 (known-good, ~38us).
// ---------------------------------------------------------------------------
__global__ __launch_bounds__(256, 2) void q_out_kernel(
    const float* __restrict__ x, const uint16_t* __restrict__ wq,
    const float* __restrict__ bq, const float* __restrict__ s_in,
    const float* __restrict__ gamma, float* __restrict__ out) {
  extern __shared__ uint8_t lds[];
  uint8_t* ldsx = lds;
  uint8_t* ldswA = lds + LDSX6;
  uint8_t* ldswB = lds + LDSX6 + 8192;
  const int tid = threadIdx.x;
  const int l = tid & 63, ng = tid >> 6;
  int bid = (int)(blockIdx.x & 7) * 256 + (int)(blockIdx.x >> 3);  // XCD swizzle
  const int rg = bid & 15, slice = bid >> 4;
  const int b = slice >> 4, t = slice & 15;
  const int w0 = rg * 4;
  const float* xs = x + ((size_t)b * 1024 + t) * 4096;
  const int lm = l & 31, lh = l >> 5;

  #pragma unroll
  for (int k = 0; k < 2; ++k)  // tap0 weights (8KB) via DMA
    gld16(wq + (size_t)(tid + k * 256) * 8, ldswA + (uint32_t)(tid + k * 256) * 16u);
  stage_halo66(ldsx, tid, 6);
  #pragma unroll
  for (int k = 0; k < 3; ++k) stage_unit66(ldsx, xs, w0, tid + k * 256);
  SCHED0; WAIT0; BAR; SCHED0;

  f32x16 acc[2][2];
  #pragma unroll
  for (int mt = 0; mt < 2; ++mt)
    #pragma unroll
    for (int nt = 0; nt < 2; ++nt)
      #pragma unroll
      for (int q = 0; q < 16; ++q) acc[mt][nt][q] = 0.f;

  #pragma unroll
  for (int tap = 0; tap < 9; ++tap) {
    const int dy = tap / 3, dx = tap % 3;
    const uint8_t* bufc = (tap & 1) ? ldswB : ldswA;
    uint8_t* bufn = (tap & 1) ? ldswA : ldswB;
    if (tap < 8) {
      #pragma unroll
      for (int k = 0; k < 2; ++k)
        gld16(wq + ((size_t)(tap + 1) * 512 + tid + k * 256) * 8,
              bufn + (uint32_t)(tid + k * 256) * 16u);
    }
    __builtin_amdgcn_s_setprio(1);
    #pragma unroll
    for (int s = 0; s < 4; ++s) {
      int oct = s * 2 + lh;
      bf16x8 a0 = ldw_q(bufc, oct, lm);
      bf16x8 a1 = ldw_q(bufc, oct, 32 + lm);
      bf16x8 b0 = ldx(ldsx, ng + dy, oct, lm + dx);
      bf16x8 b1 = ldx(ldsx, ng + dy, oct, 32 + lm + dx);
      acc[0][0] = MFMA32(a0, b0, acc[0][0]);
      acc[0][1] = MFMA32(a0, b1, acc[0][1]);
      acc[1][0] = MFMA32(a1, b0, acc[1][0]);
      acc[1][1] = MFMA32(a1, b1, acc[1][1]);
    }
    __builtin_amdgcn_s_setprio(0);
    SCHED0; WAIT0; BAR; SCHED0;
  }

  float g = gamma[0];
  const float* sb = s_in + (b * 16 + t) * 64;
  int w = w0 + ng;
  #pragma unroll
  for (int mt = 0; mt < 2; ++mt) {
    #pragma unroll
    for (int q = 0; q < 16; ++q) {
      int cl = (q & 3) + 8 * (q >> 2) + 4 * lh;
      int c  = mt * 32 + cl;
      float qb = bq[c], sc = sb[c];
      #pragma unroll
      for (int nt = 0; nt < 2; ++nt) {
        int h = nt * 32 + lm;
        uint32_t xb = (uint32_t)(((ng + 1) * 8 + (c >> 3)) * 66 + (h + 1)) * 16u
                    + (uint32_t)(c & 7) * 2u;
        float xv = bf2f(*(const uint16_t*)(ldsx + xb));
        size_t idx = ((size_t)(b * 64 + c) * 16 + t) * 4096 + (size_t)w * 64 + h;
        out[idx] = g * (acc[mt][nt][q] + qb) * sc + xv;
      }
    }
  }
}

extern "C" void kernel_launch(void* const* d_in, const int* in_sizes, int n_in,
                              void* d_out, int out_size, void* d_ws, size_t ws_size,
                              hipStream_t stream) {
  const float* x   = (const float*)d_in[0];
  const float* wq  = (const float*)d_in[1];
  const float* wk  = (const float*)d_in[2];
  const float* wv  = (const float*)d_in[3];
  const float* bq  = (const float*)d_in[4];
  const float* bk  = (const float*)d_in[5];
  const float* bv  = (const float*)d_in[6];
  const float* gam = (const float*)d_in[7];

  uint16_t* wbf = (uint16_t*)d_ws;                    // 221184 B
  float* sbuf   = (float*)((uint8_t*)d_ws + 221184);  // 32 KB

  hipMemsetAsync(sbuf, 0, 8 * 16 * 64 * sizeof(float), stream);
  prep_weights<<<(110592 + 255) / 256, 256, 0, stream>>>(wq, wk, wv, wbf);
  kv_s_kernel<<<2048, 256, LDSK, stream>>>(x, wbf + 36864, bk, bv, sbuf);
  q_out_kernel<<<2048, 256, LDSX6 + 16384, stream>>>(x, wbf, bq, sbuf, gam, (float*)d_out);
}

// Round 23
// 152.490 us; speedup vs baseline: 1.4423x; 1.4423x over previous
//
#include <hip/hip_runtime.h>
#include <hip/hip_bf16.h>
#include <stdint.h>

typedef __attribute__((ext_vector_type(8))) short bf16x8;
typedef __attribute__((ext_vector_type(4))) float f32x4v;
typedef __attribute__((ext_vector_type(16))) float f32x16;
typedef __attribute__((ext_vector_type(4))) unsigned int u32x4;

#define CH_STRIDE 65536  // T*W*H

__device__ __forceinline__ uint16_t f2bf(float f) {
  uint32_t u = __builtin_bit_cast(uint32_t, f);
  u = (u + 0x7FFFu + ((u >> 16) & 1u)) >> 16;
  return (uint16_t)u;
}
__device__ __forceinline__ float bf2f(uint32_t b) {
  return __builtin_bit_cast(float, b << 16);
}
__device__ __forceinline__ uint16_t cvt_bf(float f) {
  return __builtin_bit_cast(uint16_t, __float2bfloat16(f));
}
__device__ __forceinline__ bf16x8 andm(bf16x8 v, uint32_t m) {
  u32x4 u = __builtin_bit_cast(u32x4, v);
  u[0] &= m; u[1] &= m; u[2] &= m; u[3] &= m;
  return __builtin_bit_cast(bf16x8, u);
}

#define MFMA32(a, b, c) __builtin_amdgcn_mfma_f32_32x32x16_bf16(a, b, c, 0, 0, 0)
#define WAIT0 asm volatile("s_waitcnt vmcnt(0) lgkmcnt(0)" ::: "memory")
#define BAR __builtin_amdgcn_s_barrier()
#define SCHED0 __builtin_amdgcn_sched_barrier(0)

#define LDSX6  (6 * 8 * 66 * 16)   // 50688 (q x tile, WITH halo cols)
#define LDSK   (6 * 8 * 64 * 16)   // 49152 (kv x tile, interior only)

// Direct global->LDS DMA, 16B/lane (weights — linear pattern).
__device__ __forceinline__ void gld16(const void* g, void* l) {
  __builtin_amdgcn_global_load_lds(
      (const __attribute__((address_space(1))) uint32_t*)g,
      (__attribute__((address_space(3))) uint32_t*)l, 16, 0, 0);
}

// q x tile: [row][oct][col66] (halo cols 0,65 zero).
__device__ __forceinline__ bf16x8 ldx(const uint8_t* ldsx, int row, int oct, int ci) {
  return *(const bf16x8*)(ldsx + (uint32_t)((row * 8 + oct) * 66 + ci) * 16u);
}
// kv x tile: [row][oct][col64] interior only; caller clamps/masks.
__device__ __forceinline__ bf16x8 ldx64(const uint8_t* ldsx, int row, int oct, int ci) {
  return *(const bf16x8*)(ldsx + (uint32_t)((row * 8 + oct) * 64 + ci) * 16u);
}
__device__ __forceinline__ bf16x8 ldw_kv(const uint8_t* ldsw, int oct, int rowloc) {
  return *(const bf16x8*)(ldsw + (uint32_t)(oct * 128 + rowloc) * 16u);
}
__device__ __forceinline__ bf16x8 ldw_q(const uint8_t* ldsw, int oct, int row) {
  return *(const bf16x8*)(ldsw + (uint32_t)(oct * 64 + row) * 16u);
}

// scatter stage (q variant, 66-col with halo)
__device__ __forceinline__ void stage_unit66(uint8_t* ldsx, const float* xs, int w0, int u) {
  int row = u >> 7, oct = (u >> 4) & 7, g = u & 15;
  int w = w0 - 1 + row;
  uint32_t base = (uint32_t)((row * 8 + oct) * 66 + 4 * g + 1) * 16u;
  if ((unsigned)w < 64u) {
    const float* p = xs + (size_t)(oct * 8) * CH_STRIDE + w * 64 + 4 * g;
    f32x4v v[8];
    #pragma unroll
    for (int j = 0; j < 8; ++j) v[j] = *(const f32x4v*)(p + (size_t)j * CH_STRIDE);
    #pragma unroll
    for (int c = 0; c < 4; ++c) {
      bf16x8 frag;
      #pragma unroll
      for (int q = 0; q < 4; ++q) {
        frag[2 * q]     = (short)cvt_bf(v[2 * q][c]);
        frag[2 * q + 1] = (short)cvt_bf(v[2 * q + 1][c]);
      }
      *(bf16x8*)(ldsx + base + (uint32_t)c * 16u) = frag;
    }
  } else {
    bf16x8 z = {};
    #pragma unroll
    for (int c = 0; c < 4; ++c) *(bf16x8*)(ldsx + base + (uint32_t)c * 16u) = z;
  }
}
// scatter stage (kv variant, 64-col interior)
__device__ __forceinline__ void stage_unit64(uint8_t* ldsx, const float* xs, int w0, int u) {
  int row = u >> 7, oct = (u >> 4) & 7, g = u & 15;
  int w = w0 - 1 + row;
  uint32_t base = (uint32_t)((row * 8 + oct) * 64 + 4 * g) * 16u;
  if ((unsigned)w < 64u) {
    const float* p = xs + (size_t)(oct * 8) * CH_STRIDE + w * 64 + 4 * g;
    f32x4v v[8];
    #pragma unroll
    for (int j = 0; j < 8; ++j) v[j] = *(const f32x4v*)(p + (size_t)j * CH_STRIDE);
    #pragma unroll
    for (int c = 0; c < 4; ++c) {
      bf16x8 frag;
      #pragma unroll
      for (int q = 0; q < 4; ++q) {
        frag[2 * q]     = (short)cvt_bf(v[2 * q][c]);
        frag[2 * q + 1] = (short)cvt_bf(v[2 * q + 1][c]);
      }
      *(bf16x8*)(ldsx + base + (uint32_t)c * 16u) = frag;
    }
  } else {
    bf16x8 z = {};
    #pragma unroll
    for (int c = 0; c < 4; ++c) *(bf16x8*)(ldsx + base + (uint32_t)c * 16u) = z;
  }
}
__device__ __forceinline__ void stage_halo66(uint8_t* ldsx, int tid, int nrow) {
  if (tid < nrow * 16) {
    int row = tid >> 4, rem = tid & 15;
    int oct = rem >> 1, side = rem & 1;
    bf16x8 z = {};
    *(bf16x8*)(ldsx + (uint32_t)((row * 8 + oct) * 66 + side * 65) * 16u) = z;
  }
}

// ---------------------------------------------------------------------------
// prep: fp32 [o][i][tap] -> bf16 tap-contiguous tables (q then kv).
// ---------------------------------------------------------------------------
__global__ void prep_weights(const float* __restrict__ wq, const float* __restrict__ wk,
                             const float* __restrict__ wv, uint16_t* __restrict__ wout) {
  int i = blockIdx.x * 256 + threadIdx.x;
  if (i >= 110592) return;
  if (i < 36864) {
    int tap = i >> 12, oct = (i >> 9) & 7, row = (i >> 3) & 63, j = i & 7;
    wout[i] = f2bf(wq[(row * 64 + oct * 8 + j) * 9 + tap]);
  } else {
    int m = i - 36864;
    int tap = m >> 13, oct = (m >> 10) & 7, rl = (m >> 3) & 127, j = m & 7;
    const float* src = (rl < 64) ? wk : wv;
    wout[i] = f2bf(src[((rl & 63) * 64 + oct * 8 + j) * 9 + tap]);
  }
}

// ---------------------------------------------------------------------------
// KV kernel: 256 thr / 4 waves; wave = 1 output row; M=4 weight tiles in a
// SINGLE 16KB LDS buffer -> block LDS = 64KB -> 2 blocks/CU (cross-block
// stage/compute overlap). Per tap: MFMA(buf) -> BAR -> DMA tap+1 -> WAIT -> BAR.
// ---------------------------------------------------------------------------
__global__ __launch_bounds__(256, 2) void kv_s_kernel(
    const float* __restrict__ x, const uint16_t* __restrict__ wkv,
    const float* __restrict__ bk, const float* __restrict__ bv,
    float* __restrict__ s_out) {
  extern __shared__ uint8_t lds[];
  uint8_t* ldsx = lds;
  uint8_t* ldsw = lds + LDSK;
  const int tid = threadIdx.x;
  const int l = tid & 63;
  const int ng = tid >> 6;  // wave = output row 0..3
  int bid = (int)(blockIdx.x & 7) * 256 + (int)(blockIdx.x >> 3);  // XCD swizzle
  const int rg = bid & 15, slice = bid >> 4;
  const int b = slice >> 4, t = slice & 15;
  const int w0 = rg * 4;
  const float* xs = x + ((size_t)b * 1024 + t) * 4096;
  const int lm = l & 31, lh = l >> 5;
  const uint32_t mz0 = (lm == 0) ? 0u : ~0u;   // b0 halo mask at dx=0
  const uint32_t mz1 = (lm == 31) ? 0u : ~0u;  // b1 halo mask at dx=2

  // tap0 weights via DMA (16KB), then scatter-stage x interior
  #pragma unroll
  for (int k = 0; k < 4; ++k)
    gld16(wkv + (size_t)(tid + k * 256) * 8, ldsw + (uint32_t)(tid + k * 256) * 16u);
  #pragma unroll
  for (int k = 0; k < 3; ++k) stage_unit64(ldsx, xs, w0, tid + k * 256);
  SCHED0; WAIT0; BAR; SCHED0;

  f32x16 accK[2][2], accV[2][2];  // [mt channel-half][nt col-half]
  #pragma unroll
  for (int mt = 0; mt < 2; ++mt)
    #pragma unroll
    for (int nt = 0; nt < 2; ++nt)
      #pragma unroll
      for (int q = 0; q < 16; ++q) { accK[mt][nt][q] = 0.f; accV[mt][nt][q] = 0.f; }

  #pragma unroll
  for (int tap = 0; tap < 9; ++tap) {
    const int dy = tap / 3, dx = tap % 3;
    __builtin_amdgcn_s_setprio(1);
    #pragma unroll
    for (int s = 0; s < 4; ++s) {
      int oct = s * 2 + lh;
      bf16x8 aK0 = ldw_kv(ldsw, oct, lm);
      bf16x8 aK1 = ldw_kv(ldsw, oct, 32 + lm);
      bf16x8 aV0 = ldw_kv(ldsw, oct, 64 + lm);
      bf16x8 aV1 = ldw_kv(ldsw, oct, 96 + lm);
      bf16x8 b0  = ldx64(ldsx, ng + dy, oct, (lm + dx - 1) & 63);
      bf16x8 b1  = ldx64(ldsx, ng + dy, oct, (32 + lm + dx - 1) & 63);
      if (dx == 0) b0 = andm(b0, mz0);
      if (dx == 2) b1 = andm(b1, mz1);
      accK[0][0] = MFMA32(aK0, b0, accK[0][0]);
      accK[0][1] = MFMA32(aK0, b1, accK[0][1]);
      accK[1][0] = MFMA32(aK1, b0, accK[1][0]);
      accK[1][1] = MFMA32(aK1, b1, accK[1][1]);
      accV[0][0] = MFMA32(aV0, b0, accV[0][0]);
      accV[0][1] = MFMA32(aV0, b1, accV[0][1]);
      accV[1][0] = MFMA32(aV1, b0, accV[1][0]);
      accV[1][1] = MFMA32(aV1, b1, accV[1][1]);
    }
    __builtin_amdgcn_s_setprio(0);
    if (tap < 8) {
      SCHED0; BAR;   // all waves done reading ldsw(tap)
      #pragma unroll
      for (int k = 0; k < 4; ++k)
        gld16(wkv + ((size_t)(tap + 1) * 1024 + tid + k * 256) * 8,
              ldsw + (uint32_t)(tid + k * 256) * 16u);
      SCHED0; WAIT0; BAR; SCHED0;
    }
  }

  // epilogue: LDS partial-dump (stride 133), 64-thread reduce, 1 atomic/ch
  __syncthreads();
  float* red = (float*)lds;        // [c 64][133] = 34 KB (fits ldsx region)
  #pragma unroll
  for (int q = 0; q < 16; ++q) {
    int cl = (q & 3) + 8 * (q >> 2) + 4 * lh;
    #pragma unroll
    for (int mt = 0; mt < 2; ++mt) {
      int c = mt * 32 + cl;
      float bkc = bk[c], bvc = bv[c];
      float p = (accK[mt][0][q] + bkc) * (accV[mt][0][q] + bvc)
              + (accK[mt][1][q] + bkc) * (accV[mt][1][q] + bvc);
      red[c * 133 + ng * 32 + lm] = p;
    }
  }
  __syncthreads();
  if (tid < 64) {
    const float* rp = red + tid * 133;
    f32x4v a4 = {0.f, 0.f, 0.f, 0.f};
    #pragma unroll
    for (int j = 0; j < 32; ++j) a4 += *(const f32x4v*)(rp + j * 4);
    atomicAdd(s_out + (b * 16 + t) * 64 + tid, a4[0] + a4[1] + a4[2] + a4[3]);
  }
}

// ---------------------------------------------------------------------------
// Q kernel: unchanged (known-good, ~38us, 2 blocks/CU).
// ---------------------------------------------------------------------------
__global__ __launch_bounds__(256, 2) void q_out_kernel(
    const float* __restrict__ x, const uint16_t* __restrict__ wq,
    const float* __restrict__ bq, const float* __restrict__ s_in,
    const float* __restrict__ gamma, float* __restrict__ out) {
  extern __shared__ uint8_t lds[];
  uint8_t* ldsx = lds;
  uint8_t* ldswA = lds + LDSX6;
  uint8_t* ldswB = lds + LDSX6 + 8192;
  const int tid = threadIdx.x;
  const int l = tid & 63, ng = tid >> 6;
  int bid = (int)(blockIdx.x & 7) * 256 + (int)(blockIdx.x >> 3);  // XCD swizzle
  const int rg = bid & 15, slice = bid >> 4;
  const int b = slice >> 4, t = slice & 15;
  const int w0 = rg * 4;
  const float* xs = x + ((size_t)b * 1024 + t) * 4096;
  const int lm = l & 31, lh = l >> 5;

  #pragma unroll
  for (int k = 0; k < 2; ++k)  // tap0 weights (8KB) via DMA
    gld16(wq + (size_t)(tid + k * 256) * 8, ldswA + (uint32_t)(tid + k * 256) * 16u);
  stage_halo66(ldsx, tid, 6);
  #pragma unroll
  for (int k = 0; k < 3; ++k) stage_unit66(ldsx, xs, w0, tid + k * 256);
  SCHED0; WAIT0; BAR; SCHED0;

  f32x16 acc[2][2];
  #pragma unroll
  for (int mt = 0; mt < 2; ++mt)
    #pragma unroll
    for (int nt = 0; nt < 2; ++nt)
      #pragma unroll
      for (int q = 0; q < 16; ++q) acc[mt][nt][q] = 0.f;

  #pragma unroll
  for (int tap = 0; tap < 9; ++tap) {
    const int dy = tap / 3, dx = tap % 3;
    const uint8_t* bufc = (tap & 1) ? ldswB : ldswA;
    uint8_t* bufn = (tap & 1) ? ldswA : ldswB;
    if (tap < 8) {
      #pragma unroll
      for (int k = 0; k < 2; ++k)
        gld16(wq + ((size_t)(tap + 1) * 512 + tid + k * 256) * 8,
              bufn + (uint32_t)(tid + k * 256) * 16u);
    }
    __builtin_amdgcn_s_setprio(1);
    #pragma unroll
    for (int s = 0; s < 4; ++s) {
      int oct = s * 2 + lh;
      bf16x8 a0 = ldw_q(bufc, oct, lm);
      bf16x8 a1 = ldw_q(bufc, oct, 32 + lm);
      bf16x8 b0 = ldx(ldsx, ng + dy, oct, lm + dx);
      bf16x8 b1 = ldx(ldsx, ng + dy, oct, 32 + lm + dx);
      acc[0][0] = MFMA32(a0, b0, acc[0][0]);
      acc[0][1] = MFMA32(a0, b1, acc[0][1]);
      acc[1][0] = MFMA32(a1, b0, acc[1][0]);
      acc[1][1] = MFMA32(a1, b1, acc[1][1]);
    }
    __builtin_amdgcn_s_setprio(0);
    SCHED0; WAIT0; BAR; SCHED0;
  }

  float g = gamma[0];
  const float* sb = s_in + (b * 16 + t) * 64;
  int w = w0 + ng;
  #pragma unroll
  for (int mt = 0; mt < 2; ++mt) {
    #pragma unroll
    for (int q = 0; q < 16; ++q) {
      int cl = (q & 3) + 8 * (q >> 2) + 4 * lh;
      int c  = mt * 32 + cl;
      float qb = bq[c], sc = sb[c];
      #pragma unroll
      for (int nt = 0; nt < 2; ++nt) {
        int h = nt * 32 + lm;
        uint32_t xb = (uint32_t)(((ng + 1) * 8 + (c >> 3)) * 66 + (h + 1)) * 16u
                    + (uint32_t)(c & 7) * 2u;
        float xv = bf2f(*(const uint16_t*)(ldsx + xb));
        size_t idx = ((size_t)(b * 64 + c) * 16 + t) * 4096 + (size_t)w * 64 + h;
        out[idx] = g * (acc[mt][nt][q] + qb) * sc + xv;
      }
    }
  }
}

extern "C" void kernel_launch(void* const* d_in, const int* in_sizes, int n_in,
                              void* d_out, int out_size, void* d_ws, size_t ws_size,
                              hipStream_t stream) {
  const float* x   = (const float*)d_in[0];
  const float* wq  = (const float*)d_in[1];
  const float* wk  = (const float*)d_in[2];
  const float* wv  = (const float*)d_in[3];
  const float* bq  = (const float*)d_in[4];
  const float* bk  = (const float*)d_in[5];
  const float* bv  = (const float*)d_in[6];
  const float* gam = (const float*)d_in[7];

  uint16_t* wbf = (uint16_t*)d_ws;                    // 221184 B
  float* sbuf   = (float*)((uint8_t*)d_ws + 221184);  // 32 KB

  hipMemsetAsync(sbuf, 0, 8 * 16 * 64 * sizeof(float), stream);
  prep_weights<<<(110592 + 255) / 256, 256, 0, stream>>>(wq, wk, wv, wbf);
  kv_s_kernel<<<2048, 256, LDSK + 16384, stream>>>(x, wbf + 36864, bk, bv, sbuf);
  q_out_kernel<<<2048, 256, LDSX6 + 16384, stream>>>(x, wbf, bq, sbuf, gam, (float*)d_out);
}

// Round 24
// 149.913 us; speedup vs baseline: 1.4671x; 1.0172x over previous
//
#include <hip/hip_runtime.h>
#include <hip/hip_bf16.h>
#include <stdint.h>

typedef __attribute__((ext_vector_type(8))) short bf16x8;
typedef __attribute__((ext_vector_type(4))) float f32x4v;
typedef __attribute__((ext_vector_type(16))) float f32x16;
typedef __attribute__((ext_vector_type(4))) unsigned int u32x4;

#define CH_STRIDE 65536  // T*W*H

__device__ __forceinline__ uint16_t f2bf(float f) {
  uint32_t u = __builtin_bit_cast(uint32_t, f);
  u = (u + 0x7FFFu + ((u >> 16) & 1u)) >> 16;
  return (uint16_t)u;
}
__device__ __forceinline__ float bf2f(uint32_t b) {
  return __builtin_bit_cast(float, b << 16);
}
__device__ __forceinline__ uint16_t cvt_bf(float f) {
  return __builtin_bit_cast(uint16_t, __float2bfloat16(f));
}
__device__ __forceinline__ bf16x8 andm(bf16x8 v, uint32_t m) {
  u32x4 u = __builtin_bit_cast(u32x4, v);
  u[0] &= m; u[1] &= m; u[2] &= m; u[3] &= m;
  return __builtin_bit_cast(bf16x8, u);
}

#define MFMA32(a, b, c) __builtin_amdgcn_mfma_f32_32x32x16_bf16(a, b, c, 0, 0, 0)
#define WAIT0 asm volatile("s_waitcnt vmcnt(0) lgkmcnt(0)" ::: "memory")
#define BAR __builtin_amdgcn_s_barrier()
#define SCHED0 __builtin_amdgcn_sched_barrier(0)

#define LDSX6  (6 * 8 * 66 * 16)   // 50688 (q x tile, WITH halo cols)
#define LDSK   (6 * 8 * 64 * 16)   // 49152 (kv x tile, interior only)

// Direct global->LDS DMA, 16B/lane (weights — linear pattern).
__device__ __forceinline__ void gld16(const void* g, void* l) {
  __builtin_amdgcn_global_load_lds(
      (const __attribute__((address_space(1))) uint32_t*)g,
      (__attribute__((address_space(3))) uint32_t*)l, 16, 0, 0);
}

// q x tile: [row][oct][col66] (halo cols 0,65 zero).
__device__ __forceinline__ bf16x8 ldx(const uint8_t* ldsx, int row, int oct, int ci) {
  return *(const bf16x8*)(ldsx + (uint32_t)((row * 8 + oct) * 66 + ci) * 16u);
}
// kv x tile: [row][oct][col64] interior only; caller clamps/masks.
__device__ __forceinline__ bf16x8 ldx64(const uint8_t* ldsx, int row, int oct, int ci) {
  return *(const bf16x8*)(ldsx + (uint32_t)((row * 8 + oct) * 64 + ci) * 16u);
}
__device__ __forceinline__ bf16x8 ldw_kv(const uint8_t* ldsw, int oct, int rowloc) {
  return *(const bf16x8*)(ldsw + (uint32_t)(oct * 128 + rowloc) * 16u);
}
__device__ __forceinline__ bf16x8 ldw_q(const uint8_t* ldsw, int oct, int row) {
  return *(const bf16x8*)(ldsw + (uint32_t)(oct * 64 + row) * 16u);
}

// scatter stage (q variant, 66-col with halo)
__device__ __forceinline__ void stage_unit66(uint8_t* ldsx, const float* xs, int w0, int u) {
  int row = u >> 7, oct = (u >> 4) & 7, g = u & 15;
  int w = w0 - 1 + row;
  uint32_t base = (uint32_t)((row * 8 + oct) * 66 + 4 * g + 1) * 16u;
  if ((unsigned)w < 64u) {
    const float* p = xs + (size_t)(oct * 8) * CH_STRIDE + w * 64 + 4 * g;
    f32x4v v[8];
    #pragma unroll
    for (int j = 0; j < 8; ++j) v[j] = *(const f32x4v*)(p + (size_t)j * CH_STRIDE);
    #pragma unroll
    for (int c = 0; c < 4; ++c) {
      bf16x8 frag;
      #pragma unroll
      for (int q = 0; q < 4; ++q) {
        frag[2 * q]     = (short)cvt_bf(v[2 * q][c]);
        frag[2 * q + 1] = (short)cvt_bf(v[2 * q + 1][c]);
      }
      *(bf16x8*)(ldsx + base + (uint32_t)c * 16u) = frag;
    }
  } else {
    bf16x8 z = {};
    #pragma unroll
    for (int c = 0; c < 4; ++c) *(bf16x8*)(ldsx + base + (uint32_t)c * 16u) = z;
  }
}
// scatter stage (kv variant, 64-col interior)
__device__ __forceinline__ void stage_unit64(uint8_t* ldsx, const float* xs, int w0, int u) {
  int row = u >> 7, oct = (u >> 4) & 7, g = u & 15;
  int w = w0 - 1 + row;
  uint32_t base = (uint32_t)((row * 8 + oct) * 64 + 4 * g) * 16u;
  if ((unsigned)w < 64u) {
    const float* p = xs + (size_t)(oct * 8) * CH_STRIDE + w * 64 + 4 * g;
    f32x4v v[8];
    #pragma unroll
    for (int j = 0; j < 8; ++j) v[j] = *(const f32x4v*)(p + (size_t)j * CH_STRIDE);
    #pragma unroll
    for (int c = 0; c < 4; ++c) {
      bf16x8 frag;
      #pragma unroll
      for (int q = 0; q < 4; ++q) {
        frag[2 * q]     = (short)cvt_bf(v[2 * q][c]);
        frag[2 * q + 1] = (short)cvt_bf(v[2 * q + 1][c]);
      }
      *(bf16x8*)(ldsx + base + (uint32_t)c * 16u) = frag;
    }
  } else {
    bf16x8 z = {};
    #pragma unroll
    for (int c = 0; c < 4; ++c) *(bf16x8*)(ldsx + base + (uint32_t)c * 16u) = z;
  }
}
__device__ __forceinline__ void stage_halo66(uint8_t* ldsx, int tid, int nrow) {
  if (tid < nrow * 16) {
    int row = tid >> 4, rem = tid & 15;
    int oct = rem >> 1, side = rem & 1;
    bf16x8 z = {};
    *(bf16x8*)(ldsx + (uint32_t)((row * 8 + oct) * 66 + side * 65) * 16u) = z;
  }
}

// ---------------------------------------------------------------------------
// prep: fp32 [o][i][tap] -> bf16 tap-contiguous tables (q then kv).
// ---------------------------------------------------------------------------
__global__ void prep_weights(const float* __restrict__ wq, const float* __restrict__ wk,
                             const float* __restrict__ wv, uint16_t* __restrict__ wout) {
  int i = blockIdx.x * 256 + threadIdx.x;
  if (i >= 110592) return;
  if (i < 36864) {
    int tap = i >> 12, oct = (i >> 9) & 7, row = (i >> 3) & 63, j = i & 7;
    wout[i] = f2bf(wq[(row * 64 + oct * 8 + j) * 9 + tap]);
  } else {
    int m = i - 36864;
    int tap = m >> 13, oct = (m >> 10) & 7, rl = (m >> 3) & 127, j = m & 7;
    const float* src = (rl < 64) ? wk : wv;
    wout[i] = f2bf(src[((rl & 63) * 64 + oct * 8 + j) * 9 + tap]);
  }
}

// ---------------------------------------------------------------------------
// KV kernel (R21 best config): 256 thr / 4 waves; wave = 1 output row; M=4
// weight tiles per wave; 2x16KB dbuf weights via DMA riding under the MFMA
// cluster; 1 barrier per tap; h-halo via lane masks (interior-only x tile).
// ---------------------------------------------------------------------------
__global__ __launch_bounds__(256, 2) void kv_s_kernel(
    const float* __restrict__ x, const uint16_t* __restrict__ wkv,
    const float* __restrict__ bk, const float* __restrict__ bv,
    float* __restrict__ s_out) {
  extern __shared__ uint8_t lds[];
  uint8_t* ldsx = lds;
  uint8_t* ldswA = lds + LDSK;
  uint8_t* ldswB = lds + LDSK + 16384;
  const int tid = threadIdx.x;
  const int l = tid & 63;
  const int ng = tid >> 6;  // wave = output row 0..3
  int bid = (int)(blockIdx.x & 7) * 256 + (int)(blockIdx.x >> 3);  // XCD swizzle
  const int rg = bid & 15, slice = bid >> 4;
  const int b = slice >> 4, t = slice & 15;
  const int w0 = rg * 4;
  const float* xs = x + ((size_t)b * 1024 + t) * 4096;
  const int lm = l & 31, lh = l >> 5;
  const uint32_t mz0 = (lm == 0) ? 0u : ~0u;   // b0 halo mask at dx=0
  const uint32_t mz1 = (lm == 31) ? 0u : ~0u;  // b1 halo mask at dx=2

  // weights tap0 via DMA (16KB = 4 x 4KB), then scatter-stage x interior
  #pragma unroll
  for (int k = 0; k < 4; ++k)
    gld16(wkv + (size_t)(tid + k * 256) * 8, ldswA + (uint32_t)(tid + k * 256) * 16u);
  #pragma unroll
  for (int k = 0; k < 3; ++k) stage_unit64(ldsx, xs, w0, tid + k * 256);
  SCHED0; WAIT0; BAR; SCHED0;

  f32x16 accK[2][2], accV[2][2];  // [mt channel-half][nt col-half]
  #pragma unroll
  for (int mt = 0; mt < 2; ++mt)
    #pragma unroll
    for (int nt = 0; nt < 2; ++nt)
      #pragma unroll
      for (int q = 0; q < 16; ++q) { accK[mt][nt][q] = 0.f; accV[mt][nt][q] = 0.f; }

  #pragma unroll
  for (int tap = 0; tap < 9; ++tap) {
    const int dy = tap / 3, dx = tap % 3;
    const uint8_t* bufc = (tap & 1) ? ldswB : ldswA;
    uint8_t* bufn = (tap & 1) ? ldswA : ldswB;
    if (tap < 8) {  // DMA tap+1 weights; rides under this tap's MFMA
      #pragma unroll
      for (int k = 0; k < 4; ++k)
        gld16(wkv + ((size_t)(tap + 1) * 1024 + tid + k * 256) * 8,
              bufn + (uint32_t)(tid + k * 256) * 16u);
    }
    __builtin_amdgcn_s_setprio(1);
    #pragma unroll
    for (int s = 0; s < 4; ++s) {
      int oct = s * 2 + lh;
      bf16x8 aK0 = ldw_kv(bufc, oct, lm);
      bf16x8 aK1 = ldw_kv(bufc, oct, 32 + lm);
      bf16x8 aV0 = ldw_kv(bufc, oct, 64 + lm);
      bf16x8 aV1 = ldw_kv(bufc, oct, 96 + lm);
      bf16x8 b0  = ldx64(ldsx, ng + dy, oct, (lm + dx - 1) & 63);
      bf16x8 b1  = ldx64(ldsx, ng + dy, oct, (32 + lm + dx - 1) & 63);
      if (dx == 0) b0 = andm(b0, mz0);
      if (dx == 2) b1 = andm(b1, mz1);
      accK[0][0] = MFMA32(aK0, b0, accK[0][0]);
      accK[0][1] = MFMA32(aK0, b1, accK[0][1]);
      accK[1][0] = MFMA32(aK1, b0, accK[1][0]);
      accK[1][1] = MFMA32(aK1, b1, accK[1][1]);
      accV[0][0] = MFMA32(aV0, b0, accV[0][0]);
      accV[0][1] = MFMA32(aV0, b1, accV[0][1]);
      accV[1][0] = MFMA32(aV1, b0, accV[1][0]);
      accV[1][1] = MFMA32(aV1, b1, accV[1][1]);
    }
    __builtin_amdgcn_s_setprio(0);
    SCHED0; WAIT0; BAR; SCHED0;
  }

  // epilogue: LDS partial-dump (stride 133), 64-thread reduce, 1 atomic/ch
  __syncthreads();
  float* red = (float*)lds;        // [c 64][133] = 34 KB (fits ldsx region)
  #pragma unroll
  for (int q = 0; q < 16; ++q) {
    int cl = (q & 3) + 8 * (q >> 2) + 4 * lh;
    #pragma unroll
    for (int mt = 0; mt < 2; ++mt) {
      int c = mt * 32 + cl;
      float bkc = bk[c], bvc = bv[c];
      float p = (accK[mt][0][q] + bkc) * (accV[mt][0][q] + bvc)
              + (accK[mt][1][q] + bkc) * (accV[mt][1][q] + bvc);
      red[c * 133 + ng * 32 + lm] = p;
    }
  }
  __syncthreads();
  if (tid < 64) {
    const float* rp = red + tid * 133;
    f32x4v a4 = {0.f, 0.f, 0.f, 0.f};
    #pragma unroll
    for (int j = 0; j < 32; ++j) a4 += *(const f32x4v*)(rp + j * 4);
    atomicAdd(s_out + (b * 16 + t) * 64 + tid, a4[0] + a4[1] + a4[2] + a4[3]);
  }
}

// ---------------------------------------------------------------------------
// Q kernel: unchanged (known-good, ~38us, 2 blocks/CU).
// ---------------------------------------------------------------------------
__global__ __launch_bounds__(256, 2) void q_out_kernel(
    const float* __restrict__ x, const uint16_t* __restrict__ wq,
    const float* __restrict__ bq, const float* __restrict__ s_in,
    const float* __restrict__ gamma, float* __restrict__ out) {
  extern __shared__ uint8_t lds[];
  uint8_t* ldsx = lds;
  uint8_t* ldswA = lds + LDSX6;
  uint8_t* ldswB = lds + LDSX6 + 8192;
  const int tid = threadIdx.x;
  const int l = tid & 63, ng = tid >> 6;
  int bid = (int)(blockIdx.x & 7) * 256 + (int)(blockIdx.x >> 3);  // XCD swizzle
  const int rg = bid & 15, slice = bid >> 4;
  const int b = slice >> 4, t = slice & 15;
  const int w0 = rg * 4;
  const float* xs = x + ((size_t)b * 1024 + t) * 4096;
  const int lm = l & 31, lh = l >> 5;

  #pragma unroll
  for (int k = 0; k < 2; ++k)  // tap0 weights (8KB) via DMA
    gld16(wq + (size_t)(tid + k * 256) * 8, ldswA + (uint32_t)(tid + k * 256) * 16u);
  stage_halo66(ldsx, tid, 6);
  #pragma unroll
  for (int k = 0; k < 3; ++k) stage_unit66(ldsx, xs, w0, tid + k * 256);
  SCHED0; WAIT0; BAR; SCHED0;

  f32x16 acc[2][2];
  #pragma unroll
  for (int mt = 0; mt < 2; ++mt)
    #pragma unroll
    for (int nt = 0; nt < 2; ++nt)
      #pragma unroll
      for (int q = 0; q < 16; ++q) acc[mt][nt][q] = 0.f;

  #pragma unroll
  for (int tap = 0; tap < 9; ++tap) {
    const int dy = tap / 3, dx = tap % 3;
    const uint8_t* bufc = (tap & 1) ? ldswB : ldswA;
    uint8_t* bufn = (tap & 1) ? ldswA : ldswB;
    if (tap < 8) {
      #pragma unroll
      for (int k = 0; k < 2; ++k)
        gld16(wq + ((size_t)(tap + 1) * 512 + tid + k * 256) * 8,
              bufn + (uint32_t)(tid + k * 256) * 16u);
    }
    __builtin_amdgcn_s_setprio(1);
    #pragma unroll
    for (int s = 0; s < 4; ++s) {
      int oct = s * 2 + lh;
      bf16x8 a0 = ldw_q(bufc, oct, lm);
      bf16x8 a1 = ldw_q(bufc, oct, 32 + lm);
      bf16x8 b0 = ldx(ldsx, ng + dy, oct, lm + dx);
      bf16x8 b1 = ldx(ldsx, ng + dy, oct, 32 + lm + dx);
      acc[0][0] = MFMA32(a0, b0, acc[0][0]);
      acc[0][1] = MFMA32(a0, b1, acc[0][1]);
      acc[1][0] = MFMA32(a1, b0, acc[1][0]);
      acc[1][1] = MFMA32(a1, b1, acc[1][1]);
    }
    __builtin_amdgcn_s_setprio(0);
    SCHED0; WAIT0; BAR; SCHED0;
  }

  float g = gamma[0];
  const float* sb = s_in + (b * 16 + t) * 64;
  int w = w0 + ng;
  #pragma unroll
  for (int mt = 0; mt < 2; ++mt) {
    #pragma unroll
    for (int q = 0; q < 16; ++q) {
      int cl = (q & 3) + 8 * (q >> 2) + 4 * lh;
      int c  = mt * 32 + cl;
      float qb = bq[c], sc = sb[c];
      #pragma unroll
      for (int nt = 0; nt < 2; ++nt) {
        int h = nt * 32 + lm;
        uint32_t xb = (uint32_t)(((ng + 1) * 8 + (c >> 3)) * 66 + (h + 1)) * 16u
                    + (uint32_t)(c & 7) * 2u;
        float xv = bf2f(*(const uint16_t*)(ldsx + xb));
        size_t idx = ((size_t)(b * 64 + c) * 16 + t) * 4096 + (size_t)w * 64 + h;
        out[idx] = g * (acc[mt][nt][q] + qb) * sc + xv;
      }
    }
  }
}

extern "C" void kernel_launch(void* const* d_in, const int* in_sizes, int n_in,
                              void* d_out, int out_size, void* d_ws, size_t ws_size,
                              hipStream_t stream) {
  const float* x   = (const float*)d_in[0];
  const float* wq  = (const float*)d_in[1];
  const float* wk  = (const float*)d_in[2];
  const float* wv  = (const float*)d_in[3];
  const float* bq  = (const float*)d_in[4];
  const float* bk  = (const float*)d_in[5];
  const float* bv  = (const float*)d_in[6];
  const float* gam = (const float*)d_in[7];

  uint16_t* wbf = (uint16_t*)d_ws;                    // 221184 B
  float* sbuf   = (float*)((uint8_t*)d_ws + 221184);  // 32 KB

  hipMemsetAsync(sbuf, 0, 8 * 16 * 64 * sizeof(float), stream);
  prep_weights<<<(110592 + 255) / 256, 256, 0, stream>>>(wq, wk, wv, wbf);
  kv_s_kernel<<<2048, 256, LDSK + 32768, stream>>>(x, wbf + 36864, bk, bv, sbuf);
  q_out_kernel<<<2048, 256, LDSX6 + 16384, stream>>>(x, wbf, bq, sbuf, gam, (float*)d_out);
}